// Round 3
// baseline (216.358 us; speedup 1.0000x reference)
//
#include <hip/hip_runtime.h>
#include <math.h>

#define BB 8
#define TT 100
#define PP 1000
#define UU 64
#define NJ 52     // padded j count used for V regs (50 real)
#define GROW 56   // G row stride in floats (224B, 16B aligned)

// ws layout (floats):
//   xk : [800][256]  at 0        (204800)
//   ht : [800][64]   at 204800   (51200)
//   XcT: [56][1000]  at 256000   (56000)
//   G  : [800][56]   at 312000   (44800)
// total 356800 floats = 1.43 MB

// ---------------- K1: xk[bt][j] = bias[j] + sum_k xt[bt][k]*kernel[k][j] ----------------
__global__ __launch_bounds__(256) void k1_xk(const int* __restrict__ pro_id,
    const int* __restrict__ label, const float* __restrict__ X,
    const float* __restrict__ onehot, const float* __restrict__ kern,
    const float* __restrict__ bias, float* __restrict__ xk)
{
    __shared__ __align__(16) float xt[8][256];
    const int j = threadIdx.x;
    const int r0 = blockIdx.x * 8;
    for (int r = 0; r < 8; ++r) {
        int row = r0 + r;
        int pid = pro_id[row];
        int lab = label[row];
        xt[r][j] = X[pid * 128 + (j & 127)] * onehot[lab * 256 + j];
    }
    __syncthreads();
    float acc[8];
    float bj = bias[j];
#pragma unroll
    for (int r = 0; r < 8; ++r) acc[r] = bj;
    for (int k4 = 0; k4 < 256; k4 += 4) {
        float4 xv[8];
#pragma unroll
        for (int r = 0; r < 8; ++r) xv[r] = *(const float4*)&xt[r][k4];
#pragma unroll
        for (int kk = 0; kk < 4; ++kk) {
            float kv = kern[(k4 + kk) * 256 + j];
#pragma unroll
            for (int r = 0; r < 8; ++r) {
                float x = (kk == 0) ? xv[r].x : (kk == 1) ? xv[r].y : (kk == 2) ? xv[r].z : xv[r].w;
                acc[r] += x * kv;
            }
        }
    }
#pragma unroll
    for (int r = 0; r < 8; ++r) xk[(r0 + r) * 256 + j] = acc[r];
}

// ---------------- K2: sequential LSTM, one block per batch ----------------
__global__ __launch_bounds__(256) void k2_lstm(const float* __restrict__ xk,
    const float* __restrict__ rec, float* __restrict__ ht)
{
    __shared__ __align__(16) float h_sh[64];
    __shared__ float zs[256];
    const int j = threadIdx.x;
    const int b = blockIdx.x;
    float reccol[64];
#pragma unroll
    for (int u = 0; u < 64; ++u) reccol[u] = rec[u * 256 + j];
    float c = 0.f;
    if (j < 64) h_sh[j] = 0.f;
    __syncthreads();
    for (int t = 0; t < TT; ++t) {
        float z = xk[(b * TT + t) * 256 + j];
#pragma unroll
        for (int u4 = 0; u4 < 16; ++u4) {
            float4 h4 = *(const float4*)&h_sh[u4 * 4];
            z += h4.x * reccol[u4 * 4 + 0] + h4.y * reccol[u4 * 4 + 1]
               + h4.z * reccol[u4 * 4 + 2] + h4.w * reccol[u4 * 4 + 3];
        }
        float act;
        if (j >= 128 && j < 192) {
            act = 2.f / (1.f + __expf(-2.f * z)) - 1.f;   // tanh
        } else {
            act = 1.f / (1.f + __expf(-z));                // sigmoid
        }
        zs[j] = act;
        __syncthreads();
        if (j < 64) {
            float gi = zs[j], gf = zs[j + 64], gg = zs[j + 128], go = zs[j + 192];
            c = gf * c + gi * gg;
            float th = 2.f / (1.f + __expf(-2.f * c)) - 1.f;
            float h = go * th;
            h_sh[j] = h;
            ht[(b * TT + t) * 64 + j] = h;
        }
        __syncthreads();
    }
}

// ---------------- K3: XcT[j][p] = b1[j] + sum_k X[p][k]*W1[64+k][j], rows 50..55 = 0 ----
__global__ __launch_bounds__(256) void k3_xct(const float* __restrict__ X,
    const float* __restrict__ W1, const float* __restrict__ b1,
    float* __restrict__ XcT)
{
    int n = blockIdx.x * 256 + threadIdx.x;
    if (n >= GROW * PP) return;
    int jrow = n / PP;
    int p = n - jrow * PP;
    float acc = 0.f;
    if (jrow < 50) {
        acc = b1[jrow];
        for (int k = 0; k < 128; ++k)
            acc += X[p * 128 + k] * W1[(64 + k) * 50 + jrow];
    }
    XcT[n] = acc;
}

// ---------------- KG: G[row][j] = sum_u ht[row][u]*W1[u][j], cols 50..55 = 0 -----------
__global__ __launch_bounds__(64) void kg(const float* __restrict__ ht,
    const float* __restrict__ W1, float* __restrict__ G)
{
    __shared__ float hsh[64];
    const int row = blockIdx.x;
    const int j = threadIdx.x;
    hsh[j] = ht[row * 64 + j];
    __syncthreads();
    float acc = 0.f;
    if (j < 50) {
#pragma unroll
        for (int u = 0; u < 64; ++u) acc += hsh[u] * W1[u * 50 + j];
    }
    if (j < GROW) G[row * GROW + j] = acc;
}

// ---------------- K4: suffix-accumulate V[p,j] += a[s,p]*G[s,j]; emit per t-chunk -------
__global__ __launch_bounds__(256) void k4_main(const int* __restrict__ pro_id,
    const float* __restrict__ cos_X, const float* __restrict__ XcT,
    const float* __restrict__ G, const float* __restrict__ W2,
    const float* __restrict__ b2, float* __restrict__ out)
{
    const int b = blockIdx.z;
    const int p = blockIdx.y * 256 + threadIdx.x;
    const int ci = blockIdx.x;
    const int t0 = ci * 7;
    const int t1 = (t0 + 7 < TT) ? (t0 + 7) : TT;
    const bool valid = p < PP;
    const int pc = valid ? p : 0;

    float V[NJ];
#pragma unroll
    for (int jj = 0; jj < NJ; ++jj) V[jj] = XcT[jj * PP + pc];
    const float b2v = b2[0];

    for (int s = TT - 1; s >= t0; --s) {
        int pid = pro_id[b * TT + s];
        float a = cos_X[pid * PP + pc];
        const float4* G4 = (const float4*)(G + (b * TT + s) * GROW);
#pragma unroll
        for (int jv = 0; jv < 13; ++jv) {
            float4 g = G4[jv];
            V[4 * jv + 0] += a * g.x;
            V[4 * jv + 1] += a * g.y;
            V[4 * jv + 2] += a * g.z;
            V[4 * jv + 3] += a * g.w;
        }
        if (s < t1) {
            float acc = b2v;
#pragma unroll
            for (int jv = 0; jv < 12; ++jv) {
                float4 w = *(const float4*)&W2[4 * jv];
                acc += w.x * fmaxf(V[4 * jv + 0], 0.f)
                     + w.y * fmaxf(V[4 * jv + 1], 0.f)
                     + w.z * fmaxf(V[4 * jv + 2], 0.f)
                     + w.w * fmaxf(V[4 * jv + 3], 0.f);
            }
            acc += W2[48] * fmaxf(V[48], 0.f) + W2[49] * fmaxf(V[49], 0.f);
            if (valid) out[(b * TT + s) * PP + p] = acc;
        }
    }
}

extern "C" void kernel_launch(void* const* d_in, const int* in_sizes, int n_in,
                              void* d_out, int out_size, void* d_ws, size_t ws_size,
                              hipStream_t stream)
{
    const int* pro_id  = (const int*)d_in[0];
    const int* label   = (const int*)d_in[1];
    const float* X     = (const float*)d_in[3];
    const float* cos_X = (const float*)d_in[4];
    // d_in[5] trimatrix: structurally tril(ones) — suffix-sum semantics hardcoded
    const float* onehot = (const float*)d_in[6];
    const float* lk    = (const float*)d_in[7];
    const float* lr    = (const float*)d_in[8];
    const float* lb    = (const float*)d_in[9];
    const float* W1    = (const float*)d_in[10];
    const float* b1    = (const float*)d_in[11];
    const float* W2    = (const float*)d_in[12];
    const float* b2    = (const float*)d_in[13];

    float* ws  = (float*)d_ws;
    float* xk  = ws;            // 204800
    float* ht  = ws + 204800;   // 51200
    float* XcT = ws + 256000;   // 56000
    float* G   = ws + 312000;   // 44800
    float* out = (float*)d_out;

    hipLaunchKernelGGL(k1_xk,  dim3(100),      dim3(256), 0, stream, pro_id, label, X, onehot, lk, lb, xk);
    hipLaunchKernelGGL(k3_xct, dim3(219),      dim3(256), 0, stream, X, W1, b1, XcT);
    hipLaunchKernelGGL(k2_lstm,dim3(8),        dim3(256), 0, stream, xk, lr, ht);
    hipLaunchKernelGGL(kg,     dim3(800),      dim3(64),  0, stream, ht, W1, G);
    hipLaunchKernelGGL(k4_main,dim3(15, 4, 8), dim3(256), 0, stream, pro_id, cos_X, XcT, G, W2, b2, out);
}